// Round 15
// baseline (314.938 us; speedup 1.0000x reference)
//
#include <hip/hip_runtime.h>
#include <hip/hip_fp16.h>
#include <type_traits>

#define N_NODES 50000
#define N_EDGES 800000
#define WIN_BITS 9
#define WIN 512
#define NBUK ((N_NODES + WIN - 1) / WIN)   // 98
#define BCAP 16384

typedef _Float16 half8 __attribute__((ext_vector_type(8)));
typedef float floatx4 __attribute__((ext_vector_type(4)));

__device__ inline void acc8(float* a, half8 v) {
    const __half2* p = (const __half2*)&v;
    float2 f0 = __half22float2(p[0]);
    float2 f1 = __half22float2(p[1]);
    float2 f2 = __half22float2(p[2]);
    float2 f3 = __half22float2(p[3]);
    a[0] += f0.x; a[1] += f0.y; a[2] += f1.x; a[3] += f1.y;
    a[4] += f2.x; a[5] += f2.y; a[6] += f3.x; a[7] += f3.y;
}

// ---------------------------------------------------------------------------
// P0 + wfrag combined. Blocks [0,512): bucket edges by dest window.
// Blocks [512,540): W fp32 -> fp16 fragment-order conversion.
// ---------------------------------------------------------------------------
__global__ __launch_bounds__(256) void p0_wfrag(
        const int* __restrict__ ei, int* __restrict__ gcur,
        unsigned* __restrict__ arena, int E,
        const float* __restrict__ W1, const float* __restrict__ W2,
        const float* __restrict__ W3, const float* __restrict__ W4,
        _Float16* __restrict__ Wf1, _Float16* __restrict__ Wf2,
        _Float16* __restrict__ Wf3, _Float16* __restrict__ Wf4) {
    int tid = threadIdx.x;
    if (blockIdx.x >= 512) {
        int b = blockIdx.x - 512;
        const float* W; _Float16* Wf; int FO; int lb;
        if (b < 8)       { W = W1; Wf = Wf1; FO = 128; lb = b; }
        else if (b < 16) { W = W2; Wf = Wf2; FO = 128; lb = b - 8; }
        else if (b < 24) { W = W3; Wf = Wf3; FO = 128; lb = b - 16; }
        else             { W = W4; Wf = Wf4; FO = 64;  lb = b - 24; }
        int g = lb * 256 + tid;
        if (g >= 16 * FO) return;
        int col = g % FO;
        int sq = g / FO;
        int k0 = sq * 8;
        half8 hv;
        #pragma unroll
        for (int j = 0; j < 8; ++j)
            hv[j] = (_Float16)W[(size_t)(k0 + j) * FO + col];
        *(half8*)&Wf[(size_t)g * 8] = hv;
        return;
    }
    __shared__ int lcnt[NBUK];
    __shared__ int lbase[NBUK];
    int chunk = (E + 511) / 512;
    int e0 = blockIdx.x * chunk;
    int e1 = e0 + chunk; if (e1 > E) e1 = E;
    for (int b = tid; b < NBUK; b += 256) lcnt[b] = 0;
    __syncthreads();
    for (int e = e0 + tid; e < e1; e += 256) {
        int dst = ei[E + e];
        atomicAdd(&lcnt[dst >> WIN_BITS], 1);
    }
    __syncthreads();
    for (int b = tid; b < NBUK; b += 256) {
        lbase[b] = atomicAdd(&gcur[b], lcnt[b]);
        lcnt[b] = 0;
    }
    __syncthreads();
    for (int e = e0 + tid; e < e1; e += 256) {
        int dst = ei[E + e];
        int src = ei[e];
        int b = dst >> WIN_BITS;
        int pos = lbase[b] + atomicAdd(&lcnt[b], 1);
        if (pos < BCAP)
            arena[(size_t)b * BCAP + pos] = ((unsigned)src << WIN_BITS) | (unsigned)(dst & (WIN - 1));
    }
}

// ---------------------------------------------------------------------------
// build_graph: per-bucket, one pass. Local prefix over gcur -> bucket offset;
// LDS histogram; intra-bucket scan -> offsets/dinv; CSR fill.
// ---------------------------------------------------------------------------
__global__ __launch_bounds__(256) void build_graph(
        const unsigned* __restrict__ arena, const int* __restrict__ gcur,
        int* __restrict__ offsets, float* __restrict__ dinv,
        int* __restrict__ csr_src, int n, int total) {
    __shared__ int cnt[WIN];
    __shared__ int sbuf[256];
    __shared__ int bukoff_s;
    int b = blockIdx.x, tid = threadIdx.x;

    sbuf[tid] = (tid < b) ? gcur[tid] : 0;       // b <= 97 < 256
    cnt[tid] = 0; cnt[tid + 256] = 0;
    __syncthreads();
    #pragma unroll
    for (int off = 128; off > 0; off >>= 1) {
        if (tid < off) sbuf[tid] += sbuf[tid + off];
        __syncthreads();
    }
    if (tid == 0) bukoff_s = sbuf[0];

    int m = gcur[b]; if (m > BCAP) m = BCAP;
    const unsigned* a = arena + (size_t)b * BCAP;
    for (int i = tid; i < m; i += 256) atomicAdd(&cnt[a[i] & (WIN - 1)], 1);
    __syncthreads();

    int j0 = tid * 2;
    int a0 = cnt[j0], a1 = cnt[j0 + 1];
    int ts = a0 + a1;
    sbuf[tid] = ts;
    __syncthreads();
    for (int off = 1; off < 256; off <<= 1) {
        int u = (tid >= off) ? sbuf[tid - off] : 0;
        __syncthreads();
        sbuf[tid] += u;
        __syncthreads();
    }
    int pre = sbuf[tid] - ts;
    int base = b << WIN_BITS;
    int o0 = bukoff_s + pre, o1 = o0 + a0;
    int d0 = base + j0;
    if (d0 + 1 < n) {
        *(int2*)&offsets[d0] = make_int2(o0, o1);
        *(float2*)&dinv[d0] = make_float2(rsqrtf((float)(a0 + 1)), rsqrtf((float)(a1 + 1)));
    } else if (d0 < n) {
        offsets[d0] = o0;
        dinv[d0] = rsqrtf((float)(a0 + 1));
    }
    __syncthreads();
    cnt[j0] = o0; cnt[j0 + 1] = o1;              // reuse as cursors
    __syncthreads();
    for (int i = tid; i < m; i += 256) {
        unsigned e = a[i];
        int pos = atomicAdd(&cnt[e & (WIN - 1)], 1);
        csr_src[pos] = (int)(e >> WIN_BITS);
    }
    if (b == 0 && tid == 0) offsets[n] = total;
}

// ---------------------------------------------------------------------------
// MFMA GEMM (layer 1), LDS-free: W-fragments from global (L1-broadcast).
// ---------------------------------------------------------------------------
__global__ __launch_bounds__(256) void gemm_mfma_kernel(
        const float* __restrict__ x, const _Float16* __restrict__ Wfrag,
        const float* __restrict__ dinv, __half* __restrict__ h, int n) {
    constexpr int FO = 128;
    constexpr int NT = FO / 16;
    int tid = threadIdx.x;
    int ln = tid & 15;
    int q  = (tid >> 4) & 3;
    int w  = tid >> 6;
    int node = blockIdx.x * 64 + w * 16 + ln;
    int nodec = node < n ? node : n - 1;
    const float* xrow = x + (size_t)nodec * 128;

    floatx4 acc[NT];
    #pragma unroll
    for (int t = 0; t < NT; ++t) acc[t] = (floatx4){0.f, 0.f, 0.f, 0.f};

    #pragma unroll
    for (int s = 0; s < 4; ++s) {
        const float* xp = xrow + s * 32 + q * 8;
        float4 a0 = *(const float4*)xp;
        float4 a1 = *(const float4*)(xp + 4);
        half8 xf;
        xf[0] = (_Float16)a0.x; xf[1] = (_Float16)a0.y;
        xf[2] = (_Float16)a0.z; xf[3] = (_Float16)a0.w;
        xf[4] = (_Float16)a1.x; xf[5] = (_Float16)a1.y;
        xf[6] = (_Float16)a1.z; xf[7] = (_Float16)a1.w;
        int sq = s * 4 + q;
        #pragma unroll
        for (int t = 0; t < NT; ++t) {
            half8 wf = *(const half8*)&Wfrag[(size_t)(sq * FO + t * 16 + ln) * 8];
            acc[t] = __builtin_amdgcn_mfma_f32_16x16x32_f16(wf, xf, acc[t], 0, 0, 0);
        }
    }

    if (node < n) {
        float dv = dinv[node];
        __half* hrow = h + (size_t)node * FO;
        #pragma unroll
        for (int t = 0; t < NT; ++t) {
            __half2 p[2];
            p[0] = __float22half2_rn(make_float2(acc[t][0] * dv, acc[t][1] * dv));
            p[1] = __float22half2_rn(make_float2(acc[t][2] * dv, acc[t][3] * dv));
            *(uint2*)&hrow[t * 16 + q * 4] = *(const uint2*)p;
        }
    }
}

// ---------------------------------------------------------------------------
// Fused agg_i + gemm_{i+1}: block = 64 nodes, 512 threads (8 waves).
// Phase A: 4-DEEP gather pipeline. Two nodes x two edge-groups each -> 4
// independent index loads then 4 independent 256-B gathers per iteration
// (in-flight rows/wave: 2 -> 4). Quarter-wave (16 lanes x 16 B) per row.
// Phase B: MFMA with global W-fragments (no W in LDS; LDS = 17.4 KB).
// ---------------------------------------------------------------------------
template<int FO>
__global__ __launch_bounds__(512) void fused_agg_gemm(
        const _Float16* __restrict__ hin, const int* __restrict__ offsets,
        const int* __restrict__ csr_src, const float* __restrict__ dinv,
        const float* __restrict__ bias, const _Float16* __restrict__ Wfrag,
        __half* __restrict__ hout, int n) {
    constexpr int NT  = FO / 16;
    constexpr int TPW = NT / 2;                  // tiles per wave (cg in {0,1})
    __shared__ _Float16 aggL[64 * 136];          // 17.4 KB, padded stride

    int tid = threadIdx.x;
    int w = tid >> 6;
    int lane = tid & 63;
    int qw = lane >> 4, sl = lane & 15;
    float4 bb0 = *(const float4*)&bias[sl * 8];
    float4 bb1 = *(const float4*)&bias[sl * 8 + 4];

    for (int pp = 0; pp < 4; ++pp) {
        int c0 = blockIdx.x * 64 + w * 8 + pp * 2;
        if (c0 >= n) break;                      // wave-uniform
        int c1 = c0 + 1;
        bool v1 = c1 < n;
        c0 = __builtin_amdgcn_readfirstlane(c0);
        c1 = __builtin_amdgcn_readfirstlane(c1);

        float a0[8] = {0.f, 0.f, 0.f, 0.f, 0.f, 0.f, 0.f, 0.f};
        float a1[8] = {0.f, 0.f, 0.f, 0.f, 0.f, 0.f, 0.f, 0.f};
        if (qw == 0) acc8(a0, *(const half8*)&hin[(size_t)c0 * 128 + sl * 8]);
        if (v1 && qw == 0) acc8(a1, *(const half8*)&hin[(size_t)c1 * 128 + sl * 8]);

        int i0 = offsets[c0], e0 = offsets[c0 + 1];
        int i1 = v1 ? offsets[c1] : 0, e1 = v1 ? offsets[c1 + 1] : 0;

        // 4-deep main loop: 4 independent gathers in flight per iteration
        while (i0 + 7 < e0 && i1 + 7 < e1) {
            int sa0 = csr_src[i0 + qw];
            int sa1 = csr_src[i0 + 4 + qw];
            int sb0 = csr_src[i1 + qw];
            int sb1 = csr_src[i1 + 4 + qw];
            half8 va0 = *(const half8*)&hin[(size_t)sa0 * 128 + sl * 8];
            half8 va1 = *(const half8*)&hin[(size_t)sa1 * 128 + sl * 8];
            half8 vb0 = *(const half8*)&hin[(size_t)sb0 * 128 + sl * 8];
            half8 vb1 = *(const half8*)&hin[(size_t)sb1 * 128 + sl * 8];
            acc8(a0, va0); acc8(a0, va1);
            acc8(a1, vb0); acc8(a1, vb1);
            i0 += 8; i1 += 8;
        }
        // drains: 2-deep then 1-deep per node
        for (; i0 + 7 < e0; i0 += 8) {
            int sa0 = csr_src[i0 + qw];
            int sa1 = csr_src[i0 + 4 + qw];
            half8 va0 = *(const half8*)&hin[(size_t)sa0 * 128 + sl * 8];
            half8 va1 = *(const half8*)&hin[(size_t)sa1 * 128 + sl * 8];
            acc8(a0, va0); acc8(a0, va1);
        }
        for (; i0 + 3 < e0; i0 += 4) {
            int sa = csr_src[i0 + qw];
            acc8(a0, *(const half8*)&hin[(size_t)sa * 128 + sl * 8]);
        }
        if (i0 + qw < e0) {
            int sa = csr_src[i0 + qw];
            acc8(a0, *(const half8*)&hin[(size_t)sa * 128 + sl * 8]);
        }
        for (; i1 + 7 < e1; i1 += 8) {
            int sb0 = csr_src[i1 + qw];
            int sb1 = csr_src[i1 + 4 + qw];
            half8 vb0 = *(const half8*)&hin[(size_t)sb0 * 128 + sl * 8];
            half8 vb1 = *(const half8*)&hin[(size_t)sb1 * 128 + sl * 8];
            acc8(a1, vb0); acc8(a1, vb1);
        }
        for (; i1 + 3 < e1; i1 += 4) {
            int sb = csr_src[i1 + qw];
            acc8(a1, *(const half8*)&hin[(size_t)sb * 128 + sl * 8]);
        }
        if (v1 && i1 + qw < e1) {
            int sb = csr_src[i1 + qw];
            acc8(a1, *(const half8*)&hin[(size_t)sb * 128 + sl * 8]);
        }

        #pragma unroll
        for (int k = 0; k < 8; ++k) {
            a0[k] += __shfl_xor(a0[k], 16);
            a0[k] += __shfl_xor(a0[k], 32);
            a1[k] += __shfl_xor(a1[k], 16);
            a1[k] += __shfl_xor(a1[k], 32);
        }
        if (qw == 0) {
            {
                float dc = dinv[c0];
                half8 hv;
                hv[0] = (_Float16)fmaxf(fmaf(a0[0], dc, bb0.x), 0.f);
                hv[1] = (_Float16)fmaxf(fmaf(a0[1], dc, bb0.y), 0.f);
                hv[2] = (_Float16)fmaxf(fmaf(a0[2], dc, bb0.z), 0.f);
                hv[3] = (_Float16)fmaxf(fmaf(a0[3], dc, bb0.w), 0.f);
                hv[4] = (_Float16)fmaxf(fmaf(a0[4], dc, bb1.x), 0.f);
                hv[5] = (_Float16)fmaxf(fmaf(a0[5], dc, bb1.y), 0.f);
                hv[6] = (_Float16)fmaxf(fmaf(a0[6], dc, bb1.z), 0.f);
                hv[7] = (_Float16)fmaxf(fmaf(a0[7], dc, bb1.w), 0.f);
                *(half8*)&aggL[(size_t)(w * 8 + pp * 2) * 136 + sl * 8] = hv;
            }
            if (v1) {
                float dc = dinv[c1];
                half8 hv;
                hv[0] = (_Float16)fmaxf(fmaf(a1[0], dc, bb0.x), 0.f);
                hv[1] = (_Float16)fmaxf(fmaf(a1[1], dc, bb0.y), 0.f);
                hv[2] = (_Float16)fmaxf(fmaf(a1[2], dc, bb0.z), 0.f);
                hv[3] = (_Float16)fmaxf(fmaf(a1[3], dc, bb0.w), 0.f);
                hv[4] = (_Float16)fmaxf(fmaf(a1[4], dc, bb1.x), 0.f);
                hv[5] = (_Float16)fmaxf(fmaf(a1[5], dc, bb1.y), 0.f);
                hv[6] = (_Float16)fmaxf(fmaf(a1[6], dc, bb1.z), 0.f);
                hv[7] = (_Float16)fmaxf(fmaf(a1[7], dc, bb1.w), 0.f);
                *(half8*)&aggL[(size_t)(w * 8 + pp * 2 + 1) * 136 + sl * 8] = hv;
            }
        }
    }
    __syncthreads();

    // ---- phase B: MFMA. wave = (nodegroup ng 0..3, colgroup cg 0..1) ----
    int ng = w & 3, cg = w >> 2;
    int ln = tid & 15;
    int q  = (tid >> 4) & 3;
    int nl = ng * 16 + ln;                       // node local 0..63
    int node = blockIdx.x * 64 + nl;

    floatx4 acc[TPW];
    #pragma unroll
    for (int t = 0; t < TPW; ++t) acc[t] = (floatx4){0.f, 0.f, 0.f, 0.f};

    #pragma unroll
    for (int s = 0; s < 4; ++s) {
        half8 xf = *(const half8*)&aggL[(size_t)nl * 136 + s * 32 + q * 8];
        int sq = s * 4 + q;
        #pragma unroll
        for (int t = 0; t < TPW; ++t) {
            int T = cg * TPW + t;
            half8 wf = *(const half8*)&Wfrag[(size_t)(sq * FO + T * 16 + ln) * 8];
            acc[t] = __builtin_amdgcn_mfma_f32_16x16x32_f16(wf, xf, acc[t], 0, 0, 0);
        }
    }

    if (node < n) {
        float dv = dinv[node];
        __half* hrow = hout + (size_t)node * FO;
        #pragma unroll
        for (int t = 0; t < TPW; ++t) {
            int T = cg * TPW + t;
            __half2 p[2];
            p[0] = __float22half2_rn(make_float2(acc[t][0] * dv, acc[t][1] * dv));
            p[1] = __float22half2_rn(make_float2(acc[t][2] * dv, acc[t][3] * dv));
            *(uint2*)&hrow[T * 16 + q * 4] = *(const uint2*)p;
        }
    }
}

// ---------------------------------------------------------------------------
// Final aggregation (FO=64): eighth-wave (8 lanes x 16 B) gathers one 128-B
// row -> one instruction covers 8 edges; xor-8/16/32 reduce; fp32 out.
// ---------------------------------------------------------------------------
__global__ __launch_bounds__(256) void agg64_kernel(
        const _Float16* __restrict__ h, const int* __restrict__ offsets,
        const int* __restrict__ csr_src, const float* __restrict__ dinv,
        const float* __restrict__ bias, float* __restrict__ out, int n) {
    int lane = threadIdx.x & 63;
    int o = lane >> 3, sl = lane & 7;
    int c = (blockIdx.x << 2) + (threadIdx.x >> 6);
    if (c >= n) return;
    c = __builtin_amdgcn_readfirstlane(c);
    float acc[8] = {0.f, 0.f, 0.f, 0.f, 0.f, 0.f, 0.f, 0.f};
    if (o == 0)
        acc8(acc, *(const half8*)&h[(size_t)c * 64 + sl * 8]);   // self loop
    int s = offsets[c], e = offsets[c + 1];
    int i = s;
    for (; i + 15 < e; i += 16) {
        int sa = csr_src[i + o];
        int sb = csr_src[i + 8 + o];
        half8 va = *(const half8*)&h[(size_t)sa * 64 + sl * 8];
        half8 vb = *(const half8*)&h[(size_t)sb * 64 + sl * 8];
        acc8(acc, va);
        acc8(acc, vb);
    }
    for (; i + 7 < e; i += 8) {
        int sa = csr_src[i + o];
        acc8(acc, *(const half8*)&h[(size_t)sa * 64 + sl * 8]);
    }
    if (i + o < e) {
        int sa = csr_src[i + o];
        acc8(acc, *(const half8*)&h[(size_t)sa * 64 + sl * 8]);
    }
    #pragma unroll
    for (int k = 0; k < 8; ++k) {
        acc[k] += __shfl_xor(acc[k], 8);
        acc[k] += __shfl_xor(acc[k], 16);
        acc[k] += __shfl_xor(acc[k], 32);
    }
    if (o == 0) {
        float dc = dinv[c];
        float4 bb0 = *(const float4*)&bias[sl * 8];
        float4 bb1 = *(const float4*)&bias[sl * 8 + 4];
        float4 o0, o1;
        o0.x = fmaf(acc[0], dc, bb0.x); o0.y = fmaf(acc[1], dc, bb0.y);
        o0.z = fmaf(acc[2], dc, bb0.z); o0.w = fmaf(acc[3], dc, bb0.w);
        o1.x = fmaf(acc[4], dc, bb1.x); o1.y = fmaf(acc[5], dc, bb1.y);
        o1.z = fmaf(acc[6], dc, bb1.z); o1.w = fmaf(acc[7], dc, bb1.w);
        float* orow = out + (size_t)c * 64 + sl * 8;
        *(float4*)orow = o0;
        *(float4*)(orow + 4) = o1;
    }
}

// ---------------------------------------------------------------------------

extern "C" void kernel_launch(void* const* d_in, const int* in_sizes, int n_in,
                              void* d_out, int out_size, void* d_ws, size_t ws_size,
                              hipStream_t stream) {
    const float* x  = (const float*)d_in[0];
    const int*   ei = (const int*)  d_in[1];
    const float* W1 = (const float*)d_in[2];
    const float* b1 = (const float*)d_in[3];
    const float* W2 = (const float*)d_in[4];
    const float* b2 = (const float*)d_in[5];
    const float* W3 = (const float*)d_in[6];
    const float* b3 = (const float*)d_in[7];
    const float* W4 = (const float*)d_in[8];
    const float* b4 = (const float*)d_in[9];

    const int N = N_NODES, E = N_EDGES;

    char* p = (char*)d_ws;
    auto carve = [&](size_t bytes) {
        char* q = p;
        p += (bytes + 255) & ~(size_t)255;
        return (void*)q;
    };
    int*       offsets = (int*)      carve((size_t)(N + 1) * 4);
    int*       csr_src = (int*)      carve((size_t)E * 4);
    float*     dinv    = (float*)    carve((size_t)N * 4);
    int*       gcur    = (int*)      carve((size_t)NBUK * 4);
    unsigned*  arena   = (unsigned*) carve((size_t)NBUK * BCAP * 4);
    _Float16*  Wf1     = (_Float16*) carve((size_t)16 * 128 * 8 * 2);   // 32 KB
    _Float16*  Wf2     = (_Float16*) carve((size_t)16 * 128 * 8 * 2);
    _Float16*  Wf3     = (_Float16*) carve((size_t)16 * 128 * 8 * 2);
    _Float16*  Wf4     = (_Float16*) carve((size_t)16 * 64 * 8 * 2);    // 16 KB
    __half*    A1      = (__half*)   carve((size_t)N * 128 * 2);
    __half*    A2      = (__half*)   carve((size_t)N * 128 * 2);

    // ---- graph build + W conversion (3 dispatches) ----
    hipMemsetAsync(gcur, 0, (size_t)NBUK * 4, stream);
    p0_wfrag<<<540, 256, 0, stream>>>(ei, gcur, arena, E,
                                      W1, W2, W3, W4, Wf1, Wf2, Wf3, Wf4);
    build_graph<<<NBUK, 256, 0, stream>>>(arena, gcur, offsets, dinv, csr_src, N, E);

    // ---- layers (5 dispatches) ----
    const int nb64 = (N + 63) / 64;    // 782

    gemm_mfma_kernel<<<nb64, 256, 0, stream>>>(x, Wf1, dinv, A1, N);
    fused_agg_gemm<128><<<nb64, 512, 0, stream>>>((const _Float16*)A1, offsets, csr_src, dinv, b1, Wf2, A2, N);
    fused_agg_gemm<128><<<nb64, 512, 0, stream>>>((const _Float16*)A2, offsets, csr_src, dinv, b2, Wf3, A1, N);
    fused_agg_gemm<64><<<nb64, 512, 0, stream>>>((const _Float16*)A1, offsets, csr_src, dinv, b3, Wf4, A2, N);
    agg64_kernel<<<(N + 3) / 4, 256, 0, stream>>>((const _Float16*)A2, offsets, csr_src, dinv, b4, (float*)d_out, N);
}